// Round 1
// baseline (164.514 us; speedup 1.0000x reference)
//
#include <hip/hip_runtime.h>

// Problem constants (B=8, T_en=T_de=D=U=256)
#define B_DIM 8
#define T_EN 256
#define T_DE 256
#define D_DIM 256
#define U_DIM 256

// tanh(x) = 1 - 2/(exp(2x)+1), via v_exp_f32 (2^x) + v_rcp_f32.
// |error| ~1e-7 abs; saturates correctly for |x| large (inf/denorm safe).
__device__ __forceinline__ float fast_tanh(float x) {
    float e = __builtin_amdgcn_exp2f(x * 2.8853900817779268f); // exp(2x)
    return 1.0f - 2.0f * __builtin_amdgcn_rcpf(e + 1.0f);
}

// y = x @ w    x:(M,256) row-major, w:(256,256) row-major, y:(M,256)
// block = 256 threads = 4 waves; each wave computes one row (64 lanes x 4 cols).
// grid = M/4 blocks.
__global__ __launch_bounds__(256) void gemm_xw(
    const float* __restrict__ x,
    const float* __restrict__ w,
    float* __restrict__ y)
{
    const int tid  = threadIdx.x;
    const int lane = tid & 63;
    const int row  = blockIdx.x * 4 + (tid >> 6);
    const int col  = lane * 4;

    const float* xr = x + row * 256;
    float4 acc = make_float4(0.f, 0.f, 0.f, 0.f);

    #pragma unroll 4
    for (int k4 = 0; k4 < 64; ++k4) {
        const float4 xv = *(const float4*)(xr + k4 * 4);
        const float4 w0 = *(const float4*)(w + (k4 * 4 + 0) * 256 + col);
        const float4 w1 = *(const float4*)(w + (k4 * 4 + 1) * 256 + col);
        const float4 w2 = *(const float4*)(w + (k4 * 4 + 2) * 256 + col);
        const float4 w3 = *(const float4*)(w + (k4 * 4 + 3) * 256 + col);
        acc.x = fmaf(xv.x, w0.x, acc.x); acc.y = fmaf(xv.x, w0.y, acc.y);
        acc.z = fmaf(xv.x, w0.z, acc.z); acc.w = fmaf(xv.x, w0.w, acc.w);
        acc.x = fmaf(xv.y, w1.x, acc.x); acc.y = fmaf(xv.y, w1.y, acc.y);
        acc.z = fmaf(xv.y, w1.z, acc.z); acc.w = fmaf(xv.y, w1.w, acc.w);
        acc.x = fmaf(xv.z, w2.x, acc.x); acc.y = fmaf(xv.z, w2.y, acc.y);
        acc.z = fmaf(xv.z, w2.z, acc.z); acc.w = fmaf(xv.z, w2.w, acc.w);
        acc.x = fmaf(xv.w, w3.x, acc.x); acc.y = fmaf(xv.w, w3.y, acc.y);
        acc.z = fmaf(xv.w, w3.z, acc.z); acc.w = fmaf(xv.w, w3.w, acc.w);
    }
    *(float4*)(y + row * 256 + col) = acc;
}

// One block per (b, t_de). 256 threads = 4 waves.
// Stage 1: mu[e] = sum_u tanh(att_en[b,e,u] + att_de[b,t,u]) * nu[u]
//          waves split e into 4 chunks of 64; per e: float4-coalesced att_en
//          read, 4 tanh+fma per lane (u = lane*4..lane*4+3), 64-lane butterfly.
// Stage 2: softmax over e (block reduction in LDS).
// Stage 3: out[b,t,d] = de[b,t,d] + sum_e alpha[e] * en[b,e,d], thread d = tid.
__global__ __launch_bounds__(256) void attn_kernel(
    const float* __restrict__ att_en,  // (B, T_en, U)
    const float* __restrict__ att_de,  // (B, T_de, U)
    const float* __restrict__ en_seq,  // (B, T_en, D)
    const float* __restrict__ de_seq,  // (B, T_de, D)
    const float* __restrict__ nu,      // (U)
    float* __restrict__ out)           // (B, T_de, D)
{
    const int bt   = blockIdx.x;       // b*T_DE + t
    const int b    = bt >> 8;
    const int tid  = threadIdx.x;
    const int lane = tid & 63;
    const int wave = tid >> 6;

    __shared__ float s_mu[T_EN];
    __shared__ float s_red[8];

    // Per-lane att_de row and nu values, u = lane*4 .. lane*4+3
    const float4 dv = *(const float4*)(att_de + bt * U_DIM + lane * 4);
    const float4 nv = *(const float4*)(nu + lane * 4);

    const float* aen = att_en + b * (T_EN * U_DIM);

    // ---- Stage 1: mu ----
    const int e0 = wave * 64;
    for (int e = e0; e < e0 + 64; ++e) {
        const float4 av = *(const float4*)(aen + e * U_DIM + lane * 4);
        float p = fast_tanh(av.x + dv.x) * nv.x
                + fast_tanh(av.y + dv.y) * nv.y
                + fast_tanh(av.z + dv.z) * nv.z
                + fast_tanh(av.w + dv.w) * nv.w;
        #pragma unroll
        for (int off = 32; off > 0; off >>= 1)
            p += __shfl_xor(p, off, 64);
        if (lane == 0) s_mu[e] = p;
    }
    __syncthreads();

    // ---- Stage 2: softmax over e ----
    const float v = s_mu[tid];
    float m = v;
    #pragma unroll
    for (int off = 32; off > 0; off >>= 1)
        m = fmaxf(m, __shfl_xor(m, off, 64));
    if (lane == 0) s_red[wave] = m;
    __syncthreads();
    m = fmaxf(fmaxf(s_red[0], s_red[1]), fmaxf(s_red[2], s_red[3]));

    const float ex = __builtin_amdgcn_exp2f((v - m) * 1.4426950408889634f);
    float s = ex;
    #pragma unroll
    for (int off = 32; off > 0; off >>= 1)
        s += __shfl_xor(s, off, 64);
    if (lane == 0) s_red[4 + wave] = s;
    __syncthreads();
    s = (s_red[4] + s_red[5]) + (s_red[6] + s_red[7]);

    const float alpha = ex * __builtin_amdgcn_rcpf(s);
    s_mu[tid] = alpha;          // reuse s_mu as alphas
    __syncthreads();

    // ---- Stage 3: out = de + alphas @ en[b] ----
    const float* en_b = en_seq + b * (T_EN * D_DIM);
    float acc = 0.f;
    #pragma unroll 8
    for (int e = 0; e < T_EN; ++e)
        acc = fmaf(s_mu[e], en_b[e * D_DIM + tid], acc);

    out[bt * D_DIM + tid] = de_seq[bt * D_DIM + tid] + acc;
}

extern "C" void kernel_launch(void* const* d_in, const int* in_sizes, int n_in,
                              void* d_out, int out_size, void* d_ws, size_t ws_size,
                              hipStream_t stream) {
    const float* en_seq = (const float*)d_in[0];   // (B, T_en, D)
    const float* de_seq = (const float*)d_in[1];   // (B, T_de, D)
    const float* w_en   = (const float*)d_in[2];   // (D, U)
    const float* w_de   = (const float*)d_in[3];   // (D, U)
    const float* nu     = (const float*)d_in[4];   // (U, 1)
    float* out = (float*)d_out;

    float* att_en = (float*)d_ws;                        // 2 MB
    float* att_de = att_en + B_DIM * T_EN * U_DIM;       // 2 MB

    // att_en = en @ w_en ; att_de = de @ w_de   (M = 8*256 = 2048 rows each)
    gemm_xw<<<(B_DIM * T_EN) / 4, 256, 0, stream>>>(en_seq, w_en, att_en);
    gemm_xw<<<(B_DIM * T_DE) / 4, 256, 0, stream>>>(de_seq, w_de, att_de);

    attn_kernel<<<B_DIM * T_DE, 256, 0, stream>>>(att_en, att_de, en_seq,
                                                  de_seq, nu, out);
}

// Round 2
// 134.086 us; speedup vs baseline: 1.2269x; 1.2269x over previous
//
#include <hip/hip_runtime.h>

// Problem constants (B=8, T_en=T_de=D=U=256)
#define B_DIM 8
#define T_EN 256
#define T_DE 256
#define D_DIM 256
#define U_DIM 256

#define TT 4            // decoder steps per attn block (1 per wave)
#define AE_STRIDE 260   // padded LDS row stride (floats) for att_en chunk
#define AL_STRIDE 8     // padded+aligned stride for transposed alphas

#define C2LOG2E 2.8853900817779268f   // 2*log2(e): tanh(x)=1-2/(exp2(x*C)+1)
#define LOG2E   1.4426950408889634f

// ---------------------------------------------------------------------------
// Fused pair of GEMMs: att_en = en @ w_en, att_de = de @ w_de.
// x:(2048,256) row-major, w:(256,256) row-major, y:(2048,256).
// Block = 256 thr = 4 waves. Each block computes 16 rows x 256 cols.
// Wave wv owns rows r0..r0+3 (wave-uniform -> A via scalar loads);
// lanes span all 256 cols (4 per lane). w staged in LDS by k-chunks of 64.
// Grid: (2048/16, 2) = 256 blocks.
// ---------------------------------------------------------------------------
__global__ __launch_bounds__(256) void gemm2(
    const float* __restrict__ en, const float* __restrict__ de,
    const float* __restrict__ w_en, const float* __restrict__ w_de,
    float* __restrict__ att_en, float* __restrict__ att_de)
{
    const float* x = blockIdx.y ? de : en;
    const float* w = blockIdx.y ? w_de : w_en;
    float* y       = blockIdx.y ? att_de : att_en;

    const int tid  = threadIdx.x;
    const int lane = tid & 63;
    const int wv   = __builtin_amdgcn_readfirstlane(tid >> 6);
    const int r0   = blockIdx.x * 16 + wv * 4;
    const int c0   = lane << 2;

    __shared__ float ws[64 * 256];

    const float* xr0 = x + (r0 + 0) * 256;
    const float* xr1 = x + (r0 + 1) * 256;
    const float* xr2 = x + (r0 + 2) * 256;
    const float* xr3 = x + (r0 + 3) * 256;

    float4 acc0 = {0,0,0,0}, acc1 = {0,0,0,0}, acc2 = {0,0,0,0}, acc3 = {0,0,0,0};

    for (int k0 = 0; k0 < 256; k0 += 64) {
        __syncthreads();
        // stage w[k0..k0+63][:] -> LDS (coalesced float4)
        #pragma unroll
        for (int l = 0; l < 16; ++l) {
            const int f  = l * 256 + tid;
            const int kk = f >> 6;
            const int c4 = (f & 63) << 2;
            *(float4*)&ws[kk * 256 + c4] =
                *(const float4*)(w + (k0 + kk) * 256 + c4);
        }
        __syncthreads();

        #pragma unroll
        for (int g = 0; g < 16; ++g) {
            const int kk = g << 2;
            // wave-uniform A fragments -> scalar loads
            const float4 a0 = *(const float4*)(xr0 + k0 + kk);
            const float4 a1 = *(const float4*)(xr1 + k0 + kk);
            const float4 a2 = *(const float4*)(xr2 + k0 + kk);
            const float4 a3 = *(const float4*)(xr3 + k0 + kk);
            const float* a0p = (const float*)&a0;
            const float* a1p = (const float*)&a1;
            const float* a2p = (const float*)&a2;
            const float* a3p = (const float*)&a3;
            #pragma unroll
            for (int j = 0; j < 4; ++j) {
                const float4 bv = *(const float4*)&ws[(kk + j) * 256 + c0];
                acc0.x = fmaf(a0p[j], bv.x, acc0.x); acc0.y = fmaf(a0p[j], bv.y, acc0.y);
                acc0.z = fmaf(a0p[j], bv.z, acc0.z); acc0.w = fmaf(a0p[j], bv.w, acc0.w);
                acc1.x = fmaf(a1p[j], bv.x, acc1.x); acc1.y = fmaf(a1p[j], bv.y, acc1.y);
                acc1.z = fmaf(a1p[j], bv.z, acc1.z); acc1.w = fmaf(a1p[j], bv.w, acc1.w);
                acc2.x = fmaf(a2p[j], bv.x, acc2.x); acc2.y = fmaf(a2p[j], bv.y, acc2.y);
                acc2.z = fmaf(a2p[j], bv.z, acc2.z); acc2.w = fmaf(a2p[j], bv.w, acc2.w);
                acc3.x = fmaf(a3p[j], bv.x, acc3.x); acc3.y = fmaf(a3p[j], bv.y, acc3.y);
                acc3.z = fmaf(a3p[j], bv.z, acc3.z); acc3.w = fmaf(a3p[j], bv.w, acc3.w);
            }
        }
    }

    *(float4*)(y + (r0 + 0) * 256 + c0) = acc0;
    *(float4*)(y + (r0 + 1) * 256 + c0) = acc1;
    *(float4*)(y + (r0 + 2) * 256 + c0) = acc2;
    *(float4*)(y + (r0 + 3) * 256 + c0) = acc3;
}

// ---------------------------------------------------------------------------
// Attention: one block per (b, 4 decoder steps). 256 thr = 4 waves.
// Stage 1 (mu): att_en e-chunks (64 rows) staged in padded LDS; lane = e,
//   wave wv owns t = t0+wv and iterates u -> per-lane register accumulate,
//   NO cross-lane reduction. tanh via exp2+rcp.
// Stage 2: per-wave softmax over its own mu row; alphas stored transposed.
// Stage 3: out[t,d] = de[t,d] + sum_e alpha[t,e]*en[e,d]; each en load is
//   reused across the 4 t-accumulators (alpha broadcast from LDS b128).
// Grid: B * T_DE / TT = 512 blocks.
// ---------------------------------------------------------------------------
__global__ __launch_bounds__(256) void attn_kernel(
    const float* __restrict__ att_en,  // (B, T_en, U)
    const float* __restrict__ att_de,  // (B, T_de, U)
    const float* __restrict__ en_seq,  // (B, T_en, D)
    const float* __restrict__ de_seq,  // (B, T_de, D)
    const float* __restrict__ nu,      // (U)
    float* __restrict__ out)           // (B, T_de, D)
{
    const int blk  = blockIdx.x;             // 0..511
    const int b    = blk >> 6;
    const int t0   = (blk & 63) * TT;
    const int tid  = threadIdx.x;
    const int lane = tid & 63;
    const int wv   = __builtin_amdgcn_readfirstlane(tid >> 6);

    __shared__ float ae[64 * AE_STRIDE];     // 66.6 KB: one e-chunk, padded
    __shared__ float s_mu[TT][256];          // 4 KB
    __shared__ float s_al[256 * AL_STRIDE];  // 8 KB: alphas transposed [e][t]

    const float* aen = att_en + b * (T_EN * U_DIM);
    const float* ade = att_de + (b * T_DE + t0 + wv) * U_DIM;  // this wave's t

    // ---- Stage 1: mu[t][e] ----
    for (int ec = 0; ec < 4; ++ec) {
        __syncthreads();
        // stage 64 e-rows of att_en (coalesced read, padded b128 write)
        #pragma unroll
        for (int l = 0; l < 16; ++l) {
            const int f  = l * 256 + tid;
            const int i  = f >> 6;
            const int k4 = (f & 63) << 2;
            *(float4*)&ae[i * AE_STRIDE + k4] =
                *(const float4*)(aen + (ec * 64 + i) * U_DIM + k4);
        }
        __syncthreads();

        float acc = 0.f;
        #pragma unroll 4
        for (int ug = 0; ug < 64; ++ug) {
            const int u = ug << 2;
            const float4 av = *(const float4*)&ae[lane * AE_STRIDE + u];
            const float4 dv = *(const float4*)(ade + u);  // wave-uniform
            const float4 nv = *(const float4*)(nu + u);   // block-uniform
            {
                const float e0 = __builtin_amdgcn_exp2f(fmaf(av.x, C2LOG2E, dv.x * C2LOG2E));
                const float r  = __builtin_amdgcn_rcpf(e0 + 1.0f);
                acc = fmaf(nv.x, fmaf(r, -2.0f, 1.0f), acc);
            }
            {
                const float e1 = __builtin_amdgcn_exp2f(fmaf(av.y, C2LOG2E, dv.y * C2LOG2E));
                const float r  = __builtin_amdgcn_rcpf(e1 + 1.0f);
                acc = fmaf(nv.y, fmaf(r, -2.0f, 1.0f), acc);
            }
            {
                const float e2 = __builtin_amdgcn_exp2f(fmaf(av.z, C2LOG2E, dv.z * C2LOG2E));
                const float r  = __builtin_amdgcn_rcpf(e2 + 1.0f);
                acc = fmaf(nv.z, fmaf(r, -2.0f, 1.0f), acc);
            }
            {
                const float e3 = __builtin_amdgcn_exp2f(fmaf(av.w, C2LOG2E, dv.w * C2LOG2E));
                const float r  = __builtin_amdgcn_rcpf(e3 + 1.0f);
                acc = fmaf(nv.w, fmaf(r, -2.0f, 1.0f), acc);
            }
        }
        s_mu[wv][ec * 64 + lane] = acc;
    }
    __syncthreads();

    // ---- Stage 2: softmax over e, wave wv handles its own t-row ----
    const float4 mv = *(const float4*)&s_mu[wv][lane << 2];
    float m = fmaxf(fmaxf(mv.x, mv.y), fmaxf(mv.z, mv.w));
    #pragma unroll
    for (int off = 32; off > 0; off >>= 1)
        m = fmaxf(m, __shfl_xor(m, off, 64));

    const float e0 = __builtin_amdgcn_exp2f((mv.x - m) * LOG2E);
    const float e1 = __builtin_amdgcn_exp2f((mv.y - m) * LOG2E);
    const float e2 = __builtin_amdgcn_exp2f((mv.z - m) * LOG2E);
    const float e3 = __builtin_amdgcn_exp2f((mv.w - m) * LOG2E);
    float s = (e0 + e1) + (e2 + e3);
    #pragma unroll
    for (int off = 32; off > 0; off >>= 1)
        s += __shfl_xor(s, off, 64);
    const float inv = __builtin_amdgcn_rcpf(s);

    // transposed store: s_al[e][t]
    const int eb = lane << 2;
    s_al[(eb + 0) * AL_STRIDE + wv] = e0 * inv;
    s_al[(eb + 1) * AL_STRIDE + wv] = e1 * inv;
    s_al[(eb + 2) * AL_STRIDE + wv] = e2 * inv;
    s_al[(eb + 3) * AL_STRIDE + wv] = e3 * inv;
    __syncthreads();

    // ---- Stage 3: out = de + alphas @ en[b] ----
    const float* en_b = en_seq + b * (T_EN * D_DIM);
    float o0 = 0.f, o1 = 0.f, o2 = 0.f, o3 = 0.f;
    #pragma unroll 8
    for (int e = 0; e < T_EN; ++e) {
        const float  ev = en_b[e * D_DIM + tid];
        const float4 al = *(const float4*)&s_al[e * AL_STRIDE];  // broadcast
        o0 = fmaf(al.x, ev, o0);
        o1 = fmaf(al.y, ev, o1);
        o2 = fmaf(al.z, ev, o2);
        o3 = fmaf(al.w, ev, o3);
    }

    const long base = (long)(b * T_DE + t0) * D_DIM + tid;
    out[base + 0 * D_DIM] = de_seq[base + 0 * D_DIM] + o0;
    out[base + 1 * D_DIM] = de_seq[base + 1 * D_DIM] + o1;
    out[base + 2 * D_DIM] = de_seq[base + 2 * D_DIM] + o2;
    out[base + 3 * D_DIM] = de_seq[base + 3 * D_DIM] + o3;
}

extern "C" void kernel_launch(void* const* d_in, const int* in_sizes, int n_in,
                              void* d_out, int out_size, void* d_ws, size_t ws_size,
                              hipStream_t stream) {
    const float* en_seq = (const float*)d_in[0];   // (B, T_en, D)
    const float* de_seq = (const float*)d_in[1];   // (B, T_de, D)
    const float* w_en   = (const float*)d_in[2];   // (D, U)
    const float* w_de   = (const float*)d_in[3];   // (D, U)
    const float* nu     = (const float*)d_in[4];   // (U, 1)
    float* out = (float*)d_out;

    float* att_en = (float*)d_ws;                        // 2 MB
    float* att_de = att_en + B_DIM * T_EN * U_DIM;       // 2 MB

    // both projections in one launch: grid.y selects (x, w, y)
    gemm2<<<dim3(128, 2), 256, 0, stream>>>(en_seq, de_seq, w_en, w_de,
                                            att_en, att_de);

    attn_kernel<<<B_DIM * T_DE / TT, 256, 0, stream>>>(att_en, att_de, en_seq,
                                                       de_seq, nu, out);
}